// Round 1
// baseline (423.771 us; speedup 1.0000x reference)
//
#include <hip/hip_runtime.h>

typedef unsigned short u16;
typedef __attribute__((ext_vector_type(8))) short bf16x8;
typedef __attribute__((ext_vector_type(4))) float f32x4;
typedef __attribute__((ext_vector_type(4))) u16 u16x4;

#define T_TOK 16384
#define D_DIM 1024
#define NE 8

__device__ __forceinline__ u16 f2bf(float f) {
  union { float f; unsigned int u; } c; c.f = f;
  unsigned int u = c.u;
  u += 0x7fffu + ((u >> 16) & 1u);   // round-to-nearest-even
  return (u16)(u >> 16);
}

__device__ __forceinline__ float gelu_exact(float u) {
  return 0.5f * u * (1.0f + erff(u * 0.70710678118654752f));
}

__device__ __forceinline__ void gld16(const void* g, void* l) {
  __builtin_amdgcn_global_load_lds(
      (const __attribute__((address_space(1))) unsigned int*)g,
      (__attribute__((address_space(3))) unsigned int*)l, 16, 0, 0);
}

// Stage a 128-row x 64-col bf16 tile (128 bytes per row) into linear LDS [128][64].
// g0 points at tile origin (row 0, col-byte 0); stride = global row stride in bytes.
__device__ __forceinline__ void stage_tile(u16* lds, const char* g0, size_t stride,
                                           int wid, int lane) {
  const char* g = g0 + (size_t)(wid * 8 + (lane >> 3)) * stride + (size_t)((lane & 7) * 16);
  char* l = (char*)lds + wid * 1024;   // wave-uniform LDS base; HW adds lane*16
  #pragma unroll
  for (int c = 0; c < 4; ++c)
    gld16(g + (size_t)(32 * c) * stride, l + c * 4096);
}

// One BK=64 step: 32 MFMA per wave, acc[4][4] (64x64 per wave, 2x2 waves = 128x128)
__device__ __forceinline__ void mma_step(const u16* As, const u16* Bs, f32x4 acc[4][4],
                                         int wm, int wn, int lane) {
  const int r = lane & 15, kq = (lane >> 4) * 8;
  #pragma unroll
  for (int ks = 0; ks < 2; ++ks) {
    const int col = ks * 32 + kq;
    bf16x8 a[4], b[4];
    #pragma unroll
    for (int mf = 0; mf < 4; ++mf)
      a[mf] = *(const bf16x8*)&As[(wm * 64 + mf * 16 + r) * 64 + col];
    #pragma unroll
    for (int nf = 0; nf < 4; ++nf)
      b[nf] = *(const bf16x8*)&Bs[(wn * 64 + nf * 16 + r) * 64 + col];
    #pragma unroll
    for (int mf = 0; mf < 4; ++mf)
      #pragma unroll
      for (int nf = 0; nf < 4; ++nf)
        acc[mf][nf] = __builtin_amdgcn_mfma_f32_16x16x32_bf16(a[mf], b[nf], acc[mf][nf], 0, 0, 0);
  }
}

// ---------------- conversion kernels ----------------

__global__ __launch_bounds__(256) void cvt_x_kernel(const float* __restrict__ x,
                                                    u16* __restrict__ xb) {
  int i = (blockIdx.x * 256 + threadIdx.x) * 4;
  float4 v = *(const float4*)(x + i);
  u16x4 o; o.x = f2bf(v.x); o.y = f2bf(v.y); o.z = f2bf(v.z); o.w = f2bf(v.w);
  *(u16x4*)(xb + i) = o;
}

// w1[e][d][h] (d<1024,h<256) -> w1t[e][h][d] bf16
__global__ __launch_bounds__(256) void cvt_w1t_kernel(const float* __restrict__ w1,
                                                      u16* __restrict__ w1t) {
  int o = blockIdx.x * 256 + threadIdx.x;
  int e = o >> 18, rem = o & 0x3FFFF;
  int h = rem >> 10, d = rem & 1023;
  w1t[o] = f2bf(w1[(e << 18) + (d << 8) + h]);
}

// w2[e][k][n] (k<256,n<1024) -> w2t[e][n][k] bf16
__global__ __launch_bounds__(256) void cvt_w2t_kernel(const float* __restrict__ w2,
                                                      u16* __restrict__ w2t) {
  int o = blockIdx.x * 256 + threadIdx.x;
  int e = o >> 18, rem = o & 0x3FFFF;
  int n = rem >> 8, k = rem & 255;
  w2t[o] = f2bf(w2[(e << 18) + (k << 10) + n]);
}

// ---------------- gating (fp32, fused) ----------------
// block = 256 threads, 32 tokens. thread (jg,tg): jg=tid&63 owns cols jg*4..+3,
// tg=tid>>6 owns tokens tg*8..+7. acc[8 tok][4 col].
__global__ __launch_bounds__(256) void gating_kernel(
    const float* __restrict__ x, const float* __restrict__ wg1,
    const float* __restrict__ bg1, const float* __restrict__ wg2,
    const float* __restrict__ bg2, float* __restrict__ gates) {
  __shared__ float xst[64][32];     // [kk][t] transposed x chunk
  __shared__ float hs[32][264];     // gelu(h) per token (pad 264 for 16B-aligned f4)
  const int tid = threadIdx.x;
  const int jg = tid & 63, tg = tid >> 6;
  const int t0 = blockIdx.x * 32;

  float acc[8][4];
  #pragma unroll
  for (int i = 0; i < 8; ++i)
    #pragma unroll
    for (int q = 0; q < 4; ++q) acc[i][q] = 0.f;

  for (int k0 = 0; k0 < 1024; k0 += 64) {
    __syncthreads();
    {   // stage x chunk transposed: xst[kk][t]
      int t = tid & 31, kk8 = tid >> 5;   // kk8: 8 groups of 8 k
      const float* src = x + (size_t)(t0 + t) * 1024 + k0 + kk8 * 8;
      float4 a = *(const float4*)src;
      float4 b = *(const float4*)(src + 4);
      xst[kk8 * 8 + 0][t] = a.x; xst[kk8 * 8 + 1][t] = a.y;
      xst[kk8 * 8 + 2][t] = a.z; xst[kk8 * 8 + 3][t] = a.w;
      xst[kk8 * 8 + 4][t] = b.x; xst[kk8 * 8 + 5][t] = b.y;
      xst[kk8 * 8 + 6][t] = b.z; xst[kk8 * 8 + 7][t] = b.w;
    }
    __syncthreads();
    #pragma unroll 4
    for (int kk = 0; kk < 64; ++kk) {
      float4 w = *(const float4*)&wg1[(size_t)(k0 + kk) * 256 + jg * 4];
      float4 xa = *(const float4*)&xst[kk][tg * 8];
      float4 xc = *(const float4*)&xst[kk][tg * 8 + 4];
      float xv[8] = {xa.x, xa.y, xa.z, xa.w, xc.x, xc.y, xc.z, xc.w};
      #pragma unroll
      for (int i = 0; i < 8; ++i) {
        acc[i][0] += xv[i] * w.x; acc[i][1] += xv[i] * w.y;
        acc[i][2] += xv[i] * w.z; acc[i][3] += xv[i] * w.w;
      }
    }
  }

  // bias + gelu -> hs
  const float4 bg = *(const float4*)&bg1[jg * 4];
  #pragma unroll
  for (int i = 0; i < 8; ++i) {
    float4 hv;
    hv.x = gelu_exact(acc[i][0] + bg.x);
    hv.y = gelu_exact(acc[i][1] + bg.y);
    hv.z = gelu_exact(acc[i][2] + bg.z);
    hv.w = gelu_exact(acc[i][3] + bg.w);
    *(float4*)&hs[tg * 8 + i][jg * 4] = hv;
  }
  __syncthreads();

  // per-token layer2 + softmax + top2 (threads 0..31)
  if (tid < 32) {
    float lg[8];
    #pragma unroll
    for (int e = 0; e < 8; ++e) lg[e] = bg2[e];
    for (int j = 0; j < 256; ++j) {
      float hv = hs[tid][j];
      float4 wa = *(const float4*)&wg2[j * 8];
      float4 wb = *(const float4*)&wg2[j * 8 + 4];
      lg[0] += hv * wa.x; lg[1] += hv * wa.y; lg[2] += hv * wa.z; lg[3] += hv * wa.w;
      lg[4] += hv * wb.x; lg[5] += hv * wb.y; lg[6] += hv * wb.z; lg[7] += hv * wb.w;
    }
    float m = lg[0];
    #pragma unroll
    for (int e = 1; e < 8; ++e) m = fmaxf(m, lg[e]);
    float ex[8], s = 0.f;
    #pragma unroll
    for (int e = 0; e < 8; ++e) { ex[e] = expf(lg[e] - m); s += ex[e]; }
    int i1 = 0;
    #pragma unroll
    for (int e = 1; e < 8; ++e) if (lg[e] > lg[i1]) i1 = e;   // strict >: lowest idx on tie
    int i2 = (i1 == 0) ? 1 : 0;
    #pragma unroll
    for (int e = 0; e < 8; ++e) if (e != i1 && lg[e] > lg[i2]) i2 = e;
    float inv = 1.f / s;
    float go[8];
    #pragma unroll
    for (int e = 0; e < 8; ++e) go[e] = (e == i1 || e == i2) ? ex[e] * inv : 0.f;
    float* gp = &gates[(size_t)(t0 + tid) * 8];
    *(float4*)gp = make_float4(go[0], go[1], go[2], go[3]);
    *(float4*)(gp + 4) = make_float4(go[4], go[5], go[6], go[7]);
  }
}

// ---------------- pass A: h_all[e][t][h] = gate[t,e]*gelu(x@W1e + b1e), bf16 ----------------
__global__ __launch_bounds__(256) void expert_h_kernel(
    const u16* __restrict__ xb, const u16* __restrict__ w1t,
    const float* __restrict__ b1, const float* __restrict__ gates,
    u16* __restrict__ h_all) {
  __shared__ u16 As[128 * 64];
  __shared__ u16 Bs[128 * 64];
  __shared__ float gate_s[128];
  __shared__ float b1_s[128];
  const int tid = threadIdx.x, lane = tid & 63, wid = tid >> 6;
  const int e = blockIdx.z;
  const int t0 = blockIdx.x * 128;
  const int n0 = blockIdx.y * 128;
  const int wm = wid >> 1, wn = wid & 1;

  if (tid < 128) {
    gate_s[tid] = gates[(size_t)(t0 + tid) * 8 + e];
    b1_s[tid] = b1[e * 256 + n0 + tid];
  }

  f32x4 acc[4][4];
  #pragma unroll
  for (int i = 0; i < 4; ++i)
    #pragma unroll
    for (int j = 0; j < 4; ++j) acc[i][j] = (f32x4){0.f, 0.f, 0.f, 0.f};

  const char* Ab = (const char*)xb + (size_t)t0 * 2048;
  const char* Bb = (const char*)w1t + ((size_t)e * 256 + n0) * 2048;
  for (int kt = 0; kt < 16; ++kt) {
    __syncthreads();
    stage_tile(As, Ab + kt * 128, 2048, wid, lane);
    stage_tile(Bs, Bb + kt * 128, 2048, wid, lane);
    __syncthreads();
    mma_step(As, Bs, acc, wm, wn, lane);
  }

  #pragma unroll
  for (int mf = 0; mf < 4; ++mf)
    #pragma unroll
    for (int rr = 0; rr < 4; ++rr) {
      const int lt = wm * 64 + mf * 16 + ((lane >> 4) << 2) + rr;
      const float g = gate_s[lt];
      #pragma unroll
      for (int nf = 0; nf < 4; ++nf) {
        const int ln = wn * 64 + nf * 16 + (lane & 15);
        float u = acc[mf][nf][rr] + b1_s[ln];
        float h = gelu_exact(u);
        h_all[((size_t)e * T_TOK + t0 + lt) * 256 + n0 + ln] = f2bf(h * g);
      }
    }
}

// ---------------- pass B: y = sum_e h_all_e @ W2e + sum_e gate*b2 ----------------
__global__ __launch_bounds__(256) void moe_out_kernel(
    const u16* __restrict__ h_all, const u16* __restrict__ w2t,
    const float* __restrict__ b2, const float* __restrict__ gates,
    float* __restrict__ y) {
  __shared__ u16 As[128 * 64];
  __shared__ u16 Bs[128 * 64];
  __shared__ float gate_s[128][8];
  __shared__ float b2_s[8][128];
  const int tid = threadIdx.x, lane = tid & 63, wid = tid >> 6;
  const int t0 = blockIdx.x * 128;
  const int n0 = blockIdx.y * 128;
  const int wm = wid >> 1, wn = wid & 1;

  for (int i = tid; i < 1024; i += 256) {
    gate_s[i >> 3][i & 7] = gates[(size_t)(t0 + (i >> 3)) * 8 + (i & 7)];
    b2_s[i >> 7][i & 127] = b2[(size_t)(i >> 7) * 1024 + n0 + (i & 127)];
  }

  f32x4 acc[4][4];
  #pragma unroll
  for (int i = 0; i < 4; ++i)
    #pragma unroll
    for (int j = 0; j < 4; ++j) acc[i][j] = (f32x4){0.f, 0.f, 0.f, 0.f};

  for (int e = 0; e < NE; ++e) {
    const char* Ab = (const char*)h_all + ((size_t)e * T_TOK + t0) * 512;
    const char* Bb = (const char*)w2t + ((size_t)e * D_DIM + n0) * 512;
    #pragma unroll 1
    for (int kt = 0; kt < 4; ++kt) {
      __syncthreads();
      stage_tile(As, Ab + kt * 128, 512, wid, lane);
      stage_tile(Bs, Bb + kt * 128, 512, wid, lane);
      __syncthreads();
      mma_step(As, Bs, acc, wm, wn, lane);
    }
  }

  #pragma unroll
  for (int mf = 0; mf < 4; ++mf)
    #pragma unroll
    for (int rr = 0; rr < 4; ++rr) {
      const int lt = wm * 64 + mf * 16 + ((lane >> 4) << 2) + rr;
      float g8[8];
      #pragma unroll
      for (int e = 0; e < 8; ++e) g8[e] = gate_s[lt][e];
      #pragma unroll
      for (int nf = 0; nf < 4; ++nf) {
        const int ln = wn * 64 + nf * 16 + (lane & 15);
        float bias = 0.f;
        #pragma unroll
        for (int e = 0; e < 8; ++e) bias += g8[e] * b2_s[e][ln];
        y[(size_t)(t0 + lt) * 1024 + n0 + ln] = acc[mf][nf][rr] + bias;
      }
    }
}

extern "C" void kernel_launch(void* const* d_in, const int* in_sizes, int n_in,
                              void* d_out, int out_size, void* d_ws, size_t ws_size,
                              hipStream_t stream) {
  (void)in_sizes; (void)n_in; (void)out_size; (void)ws_size;
  const float* x   = (const float*)d_in[0];
  const float* wg1 = (const float*)d_in[1];
  const float* bg1 = (const float*)d_in[2];
  const float* wg2 = (const float*)d_in[3];
  const float* bg2 = (const float*)d_in[4];
  const float* w1  = (const float*)d_in[5];
  const float* b1  = (const float*)d_in[6];
  const float* w2  = (const float*)d_in[7];
  const float* b2  = (const float*)d_in[8];
  float* y = (float*)d_out;

  char* ws = (char*)d_ws;
  u16*   xb    = (u16*)(ws);                       // 33,554,432 B
  u16*   w1t   = (u16*)(ws + 33554432);            //  4,194,304 B
  u16*   w2t   = (u16*)(ws + 37748736);            //  4,194,304 B
  float* gates = (float*)(ws + 41943040);          //    524,288 B
  u16*   h_all = (u16*)(ws + 42467328);            // 67,108,864 B  (total ~104.5 MiB)

  cvt_x_kernel  <<<16384, 256, 0, stream>>>(x, xb);
  cvt_w1t_kernel<<<8192, 256, 0, stream>>>(w1, w1t);
  cvt_w2t_kernel<<<8192, 256, 0, stream>>>(w2, w2t);
  gating_kernel <<<512, 256, 0, stream>>>(x, wg1, bg1, wg2, bg2, gates);
  expert_h_kernel<<<dim3(128, 2, 8), 256, 0, stream>>>(xb, w1t, b1, gates, h_all);
  moe_out_kernel <<<dim3(128, 8), 256, 0, stream>>>(h_all, w2t, b2, gates, y);
}

// Round 2
// 382.469 us; speedup vs baseline: 1.1080x; 1.1080x over previous
//
#include <hip/hip_runtime.h>

typedef unsigned short u16;
typedef __attribute__((ext_vector_type(8))) short bf16x8;
typedef __attribute__((ext_vector_type(4))) float f32x4;
typedef __attribute__((ext_vector_type(4))) u16 u16x4;

#define T_TOK 16384
#define D_DIM 1024
#define NE 8

__device__ __forceinline__ u16 f2bf(float f) {
  union { float f; unsigned int u; } c; c.f = f;
  unsigned int u = c.u;
  u += 0x7fffu + ((u >> 16) & 1u);   // round-to-nearest-even
  return (u16)(u >> 16);
}

__device__ __forceinline__ float gelu_exact(float u) {
  return 0.5f * u * (1.0f + erff(u * 0.70710678118654752f));
}

__device__ __forceinline__ void gld16(const void* g, void* l) {
  __builtin_amdgcn_global_load_lds(
      (const __attribute__((address_space(1))) unsigned int*)g,
      (__attribute__((address_space(3))) unsigned int*)l, 16, 0, 0);
}

// Stage a 128-row x 64-col bf16 tile (128 bytes per row) into linear LDS [128][64].
__device__ __forceinline__ void stage_tile(u16* lds, const char* g0, size_t stride,
                                           int wid, int lane) {
  const char* g = g0 + (size_t)(wid * 8 + (lane >> 3)) * stride + (size_t)((lane & 7) * 16);
  char* l = (char*)lds + wid * 1024;   // wave-uniform LDS base; HW adds lane*16
  #pragma unroll
  for (int c = 0; c < 4; ++c)
    gld16(g + (size_t)(32 * c) * stride, l + c * 4096);
}

// One BK=64 step: 32 MFMA per wave, acc[4][4] (64x64 per wave, 2x2 waves = 128x128)
__device__ __forceinline__ void mma_step(const u16* As, const u16* Bs, f32x4 acc[4][4],
                                         int wm, int wn, int lane) {
  const int r = lane & 15, kq = (lane >> 4) * 8;
  #pragma unroll
  for (int ks = 0; ks < 2; ++ks) {
    const int col = ks * 32 + kq;
    bf16x8 a[4], b[4];
    #pragma unroll
    for (int mf = 0; mf < 4; ++mf)
      a[mf] = *(const bf16x8*)&As[(wm * 64 + mf * 16 + r) * 64 + col];
    #pragma unroll
    for (int nf = 0; nf < 4; ++nf)
      b[nf] = *(const bf16x8*)&Bs[(wn * 64 + nf * 16 + r) * 64 + col];
    #pragma unroll
    for (int mf = 0; mf < 4; ++mf)
      #pragma unroll
      for (int nf = 0; nf < 4; ++nf)
        acc[mf][nf] = __builtin_amdgcn_mfma_f32_16x16x32_bf16(a[mf], b[nf], acc[mf][nf], 0, 0, 0);
  }
}

// ---------------- tiled transpose+convert: in[e][R][C] f32 -> out[e][C][R] bf16 ----------------
__global__ __launch_bounds__(256) void transpose_cvt_kernel(const float* __restrict__ in,
                                                            u16* __restrict__ out,
                                                            int R, int C) {
  __shared__ u16 t[32][36];
  const int e = blockIdx.z;
  const int r0 = blockIdx.x * 32, c0 = blockIdx.y * 32;
  const int tid = threadIdx.x;
  {
    const int r = tid >> 3, cq = (tid & 7) * 4;
    float4 v = *(const float4*)(in + ((size_t)e * R + r0 + r) * C + c0 + cq);
    t[r][cq + 0] = f2bf(v.x); t[r][cq + 1] = f2bf(v.y);
    t[r][cq + 2] = f2bf(v.z); t[r][cq + 3] = f2bf(v.w);
  }
  __syncthreads();
  {
    const int c = tid >> 3, rq = (tid & 7) * 4;
    u16x4 o;
    o.x = t[rq + 0][c]; o.y = t[rq + 1][c]; o.z = t[rq + 2][c]; o.w = t[rq + 3][c];
    *(u16x4*)(out + ((size_t)e * C + c0 + c) * R + r0 + rq) = o;
  }
}

// ---------------- fused gating ----------------
// 512 threads, 32 tokens/block. Wave w owns rows w*4..w*4+3; lane tn owns cols tn*4..+3.
// Also converts its x-tile to bf16 (xb) while staging, replacing cvt_x.
__global__ __launch_bounds__(512, 4) void gating_fused_kernel(
    const float* __restrict__ x, const float* __restrict__ wg1,
    const float* __restrict__ bg1, const float* __restrict__ wg2,
    const float* __restrict__ bg2, float* __restrict__ gates,
    u16* __restrict__ xb) {
  __shared__ float As[16][36];      // transposed x chunk [k][m]
  __shared__ float Bs[16 * 256];    // wg1 chunk [k][n], linear for global_load_lds
  __shared__ float lg_lds[32][8];
  const int tid = threadIdx.x;
  const int lane = tid & 63, w = tid >> 6;   // w = wave = row group, lane = col group
  const int t0 = blockIdx.x * 32;

  float acc[4][4];
  #pragma unroll
  for (int i = 0; i < 4; ++i)
    #pragma unroll
    for (int j = 0; j < 4; ++j) acc[i][j] = 0.f;

  for (int k0 = 0; k0 < 1024; k0 += 16) {
    __syncthreads();
    // stage wg1 chunk [16][256] via global_load_lds: 2 per thread
    {
      char* l = (char*)Bs + w * 1024;
      const char* g = (const char*)wg1 + (size_t)(k0 + w) * 1024 + lane * 16;
      gld16(g, l);
      gld16(g + 8 * 1024, l + 8192);
    }
    // stage x chunk transposed (threads 0..127) + emit bf16 x
    if (tid < 128) {
      const int row = tid >> 2, f4 = tid & 3;
      const float* src = x + (size_t)(t0 + row) * 1024 + k0 + f4 * 4;
      float4 v = *(const float4*)src;
      As[f4 * 4 + 0][row] = v.x; As[f4 * 4 + 1][row] = v.y;
      As[f4 * 4 + 2][row] = v.z; As[f4 * 4 + 3][row] = v.w;
      u16x4 o; o.x = f2bf(v.x); o.y = f2bf(v.y); o.z = f2bf(v.z); o.w = f2bf(v.w);
      *(u16x4*)(xb + (size_t)(t0 + row) * 1024 + k0 + f4 * 4) = o;
    }
    __syncthreads();
    #pragma unroll
    for (int k = 0; k < 16; ++k) {
      float4 a4 = *(const float4*)&As[k][w * 4];
      float4 b4 = *(const float4*)&Bs[k * 256 + lane * 4];
      float av[4] = {a4.x, a4.y, a4.z, a4.w};
      float bv[4] = {b4.x, b4.y, b4.z, b4.w};
      #pragma unroll
      for (int i = 0; i < 4; ++i)
        #pragma unroll
        for (int j = 0; j < 4; ++j) acc[i][j] += av[i] * bv[j];
    }
  }

  // bias + gelu -> h (in registers), then logit partials over this lane's 4 cols
  const float4 bgv = *(const float4*)&bg1[lane * 4];
  float bb[4] = {bgv.x, bgv.y, bgv.z, bgv.w};
  float part[4][8];
  #pragma unroll
  for (int i = 0; i < 4; ++i)
    #pragma unroll
    for (int e = 0; e < 8; ++e) part[i][e] = 0.f;
  #pragma unroll
  for (int j = 0; j < 4; ++j) {
    float4 wa = *(const float4*)&wg2[(lane * 4 + j) * 8];
    float4 wb = *(const float4*)&wg2[(lane * 4 + j) * 8 + 4];
    float we[8] = {wa.x, wa.y, wa.z, wa.w, wb.x, wb.y, wb.z, wb.w};
    #pragma unroll
    for (int i = 0; i < 4; ++i) {
      float h = gelu_exact(acc[i][j] + bb[j]);
      #pragma unroll
      for (int e = 0; e < 8; ++e) part[i][e] += h * we[e];
    }
  }
  // full-wave butterfly reduce (64 lanes)
  #pragma unroll
  for (int mask = 1; mask < 64; mask <<= 1)
    #pragma unroll
    for (int i = 0; i < 4; ++i)
      #pragma unroll
      for (int e = 0; e < 8; ++e) part[i][e] += __shfl_xor(part[i][e], mask);
  if (lane < 8) {
    #pragma unroll
    for (int i = 0; i < 4; ++i) lg_lds[w * 4 + i][lane] = part[i][lane] + bg2[lane];
  }
  __syncthreads();

  // softmax + top2 per token (threads 0..31)
  if (tid < 32) {
    float lg[8];
    #pragma unroll
    for (int e = 0; e < 8; ++e) lg[e] = lg_lds[tid][e];
    float m = lg[0];
    #pragma unroll
    for (int e = 1; e < 8; ++e) m = fmaxf(m, lg[e]);
    float ex[8], s = 0.f;
    #pragma unroll
    for (int e = 0; e < 8; ++e) { ex[e] = expf(lg[e] - m); s += ex[e]; }
    int i1 = 0;
    #pragma unroll
    for (int e = 1; e < 8; ++e) if (lg[e] > lg[i1]) i1 = e;   // strict >: lowest idx on tie
    int i2 = (i1 == 0) ? 1 : 0;
    #pragma unroll
    for (int e = 0; e < 8; ++e) if (e != i1 && lg[e] > lg[i2]) i2 = e;
    float inv = 1.f / s;
    float go[8];
    #pragma unroll
    for (int e = 0; e < 8; ++e) go[e] = (e == i1 || e == i2) ? ex[e] * inv : 0.f;
    float* gp = &gates[(size_t)(t0 + tid) * 8];
    *(float4*)gp = make_float4(go[0], go[1], go[2], go[3]);
    *(float4*)(gp + 4) = make_float4(go[4], go[5], go[6], go[7]);
  }
}

// ---------------- pass A: h_all[e][t][h] = gate[t,e]*gelu(x@W1e + b1e), bf16 ----------------
__global__ __launch_bounds__(256) void expert_h_kernel(
    const u16* __restrict__ xb, const u16* __restrict__ w1t,
    const float* __restrict__ b1, const float* __restrict__ gates,
    u16* __restrict__ h_all) {
  __shared__ u16 As[128 * 64];
  __shared__ u16 Bs[128 * 64];
  __shared__ float gate_s[128];
  __shared__ float b1_s[128];
  const int tid = threadIdx.x, lane = tid & 63, wid = tid >> 6;
  const int e = blockIdx.z;
  const int t0 = blockIdx.x * 128;
  const int n0 = blockIdx.y * 128;
  const int wm = wid >> 1, wn = wid & 1;

  if (tid < 128) {
    gate_s[tid] = gates[(size_t)(t0 + tid) * 8 + e];
    b1_s[tid] = b1[e * 256 + n0 + tid];
  }

  f32x4 acc[4][4];
  #pragma unroll
  for (int i = 0; i < 4; ++i)
    #pragma unroll
    for (int j = 0; j < 4; ++j) acc[i][j] = (f32x4){0.f, 0.f, 0.f, 0.f};

  const char* Ab = (const char*)xb + (size_t)t0 * 2048;
  const char* Bb = (const char*)w1t + ((size_t)e * 256 + n0) * 2048;
  for (int kt = 0; kt < 16; ++kt) {
    __syncthreads();
    stage_tile(As, Ab + kt * 128, 2048, wid, lane);
    stage_tile(Bs, Bb + kt * 128, 2048, wid, lane);
    __syncthreads();
    mma_step(As, Bs, acc, wm, wn, lane);
  }

  #pragma unroll
  for (int mf = 0; mf < 4; ++mf)
    #pragma unroll
    for (int rr = 0; rr < 4; ++rr) {
      const int lt = wm * 64 + mf * 16 + ((lane >> 4) << 2) + rr;
      const float g = gate_s[lt];
      #pragma unroll
      for (int nf = 0; nf < 4; ++nf) {
        const int ln = wn * 64 + nf * 16 + (lane & 15);
        float u = acc[mf][nf][rr] + b1_s[ln];
        float h = gelu_exact(u);
        h_all[((size_t)e * T_TOK + t0 + lt) * 256 + n0 + ln] = f2bf(h * g);
      }
    }
}

// ---------------- pass B: y = sum_e h_all_e @ W2e + sum_e gate*b2 ----------------
__global__ __launch_bounds__(256) void moe_out_kernel(
    const u16* __restrict__ h_all, const u16* __restrict__ w2t,
    const float* __restrict__ b2, const float* __restrict__ gates,
    float* __restrict__ y) {
  __shared__ u16 As[128 * 64];
  __shared__ u16 Bs[128 * 64];
  __shared__ float gate_s[128][8];
  __shared__ float b2_s[8][128];
  const int tid = threadIdx.x, lane = tid & 63, wid = tid >> 6;
  const int t0 = blockIdx.x * 128;
  const int n0 = blockIdx.y * 128;
  const int wm = wid >> 1, wn = wid & 1;

  for (int i = tid; i < 1024; i += 256) {
    gate_s[i >> 3][i & 7] = gates[(size_t)(t0 + (i >> 3)) * 8 + (i & 7)];
    b2_s[i >> 7][i & 127] = b2[(size_t)(i >> 7) * 1024 + n0 + (i & 127)];
  }

  f32x4 acc[4][4];
  #pragma unroll
  for (int i = 0; i < 4; ++i)
    #pragma unroll
    for (int j = 0; j < 4; ++j) acc[i][j] = (f32x4){0.f, 0.f, 0.f, 0.f};

  for (int e = 0; e < NE; ++e) {
    const char* Ab = (const char*)h_all + ((size_t)e * T_TOK + t0) * 512;
    const char* Bb = (const char*)w2t + ((size_t)e * D_DIM + n0) * 512;
    #pragma unroll 1
    for (int kt = 0; kt < 4; ++kt) {
      __syncthreads();
      stage_tile(As, Ab + kt * 128, 512, wid, lane);
      stage_tile(Bs, Bb + kt * 128, 512, wid, lane);
      __syncthreads();
      mma_step(As, Bs, acc, wm, wn, lane);
    }
  }

  #pragma unroll
  for (int mf = 0; mf < 4; ++mf)
    #pragma unroll
    for (int rr = 0; rr < 4; ++rr) {
      const int lt = wm * 64 + mf * 16 + ((lane >> 4) << 2) + rr;
      float g8[8];
      #pragma unroll
      for (int e = 0; e < 8; ++e) g8[e] = gate_s[lt][e];
      #pragma unroll
      for (int nf = 0; nf < 4; ++nf) {
        const int ln = wn * 64 + nf * 16 + (lane & 15);
        float bias = 0.f;
        #pragma unroll
        for (int e = 0; e < 8; ++e) bias += g8[e] * b2_s[e][ln];
        y[(size_t)(t0 + lt) * 1024 + n0 + ln] = acc[mf][nf][rr] + bias;
      }
    }
}

extern "C" void kernel_launch(void* const* d_in, const int* in_sizes, int n_in,
                              void* d_out, int out_size, void* d_ws, size_t ws_size,
                              hipStream_t stream) {
  (void)in_sizes; (void)n_in; (void)out_size; (void)ws_size;
  const float* x   = (const float*)d_in[0];
  const float* wg1 = (const float*)d_in[1];
  const float* bg1 = (const float*)d_in[2];
  const float* wg2 = (const float*)d_in[3];
  const float* bg2 = (const float*)d_in[4];
  const float* w1  = (const float*)d_in[5];
  const float* b1  = (const float*)d_in[6];
  const float* w2  = (const float*)d_in[7];
  const float* b2  = (const float*)d_in[8];
  float* y = (float*)d_out;

  char* ws = (char*)d_ws;
  u16*   xb    = (u16*)(ws);                       // 33,554,432 B
  u16*   w1t   = (u16*)(ws + 33554432);            //  4,194,304 B
  u16*   w2t   = (u16*)(ws + 37748736);            //  4,194,304 B
  float* gates = (float*)(ws + 41943040);          //    524,288 B
  u16*   h_all = (u16*)(ws + 42467328);            // 67,108,864 B  (total ~104.5 MiB)

  // w1[e][1024][256] -> w1t[e][256][1024]; w2[e][256][1024] -> w2t[e][1024][256]
  transpose_cvt_kernel<<<dim3(32, 8, 8), 256, 0, stream>>>(w1, w1t, 1024, 256);
  transpose_cvt_kernel<<<dim3(8, 32, 8), 256, 0, stream>>>(w2, w2t, 256, 1024);
  gating_fused_kernel<<<512, 512, 0, stream>>>(x, wg1, bg1, wg2, bg2, gates, xb);
  expert_h_kernel<<<dim3(128, 2, 8), 256, 0, stream>>>(xb, w1t, b1, gates, h_all);
  moe_out_kernel <<<dim3(128, 8), 256, 0, stream>>>(h_all, w2t, b2, gates, y);
}

// Round 3
// 375.430 us; speedup vs baseline: 1.1288x; 1.0187x over previous
//
#include <hip/hip_runtime.h>

typedef unsigned short u16;
typedef __attribute__((ext_vector_type(8))) short bf16x8;
typedef __attribute__((ext_vector_type(4))) float f32x4;
typedef __attribute__((ext_vector_type(4))) u16 u16x4;

#define T_TOK 16384
#define D_DIM 1024
#define NE 8

__device__ __forceinline__ u16 f2bf(float f) {
  union { float f; unsigned int u; } c; c.f = f;
  unsigned int u = c.u;
  u += 0x7fffu + ((u >> 16) & 1u);   // round-to-nearest-even
  return (u16)(u >> 16);
}

__device__ __forceinline__ float gelu_exact(float u) {
  return 0.5f * u * (1.0f + erff(u * 0.70710678118654752f));
}

__device__ __forceinline__ void gld16(const void* g, void* l) {
  __builtin_amdgcn_global_load_lds(
      (const __attribute__((address_space(1))) unsigned int*)g,
      (__attribute__((address_space(3))) unsigned int*)l, 16, 0, 0);
}

// Stage a 128-row x 64-col bf16 tile (128 bytes per row) into linear LDS [128][64].
__device__ __forceinline__ void stage_tile(u16* lds, const char* g0, size_t stride,
                                           int wid, int lane) {
  const char* g = g0 + (size_t)(wid * 8 + (lane >> 3)) * stride + (size_t)((lane & 7) * 16);
  char* l = (char*)lds + wid * 1024;   // wave-uniform LDS base; HW adds lane*16
  #pragma unroll
  for (int c = 0; c < 4; ++c)
    gld16(g + (size_t)(32 * c) * stride, l + c * 4096);
}

// One BK=64 step: 32 MFMA per wave, acc[4][4] (64x64 per wave, 2x2 waves = 128x128)
__device__ __forceinline__ void mma_step(const u16* As, const u16* Bs, f32x4 acc[4][4],
                                         int wm, int wn, int lane) {
  const int r = lane & 15, kq = (lane >> 4) * 8;
  #pragma unroll
  for (int ks = 0; ks < 2; ++ks) {
    const int col = ks * 32 + kq;
    bf16x8 a[4], b[4];
    #pragma unroll
    for (int mf = 0; mf < 4; ++mf)
      a[mf] = *(const bf16x8*)&As[(wm * 64 + mf * 16 + r) * 64 + col];
    #pragma unroll
    for (int nf = 0; nf < 4; ++nf)
      b[nf] = *(const bf16x8*)&Bs[(wn * 64 + nf * 16 + r) * 64 + col];
    #pragma unroll
    for (int mf = 0; mf < 4; ++mf)
      #pragma unroll
      for (int nf = 0; nf < 4; ++nf)
        acc[mf][nf] = __builtin_amdgcn_mfma_f32_16x16x32_bf16(a[mf], b[nf], acc[mf][nf], 0, 0, 0);
  }
}

// ---------------- tiled transpose+convert: in[e][R][C] f32 -> out[e][C][R] bf16 ----------------
__global__ __launch_bounds__(256) void transpose_cvt_kernel(const float* __restrict__ in,
                                                            u16* __restrict__ out,
                                                            int R, int C) {
  __shared__ u16 t[32][36];
  const int e = blockIdx.z;
  const int r0 = blockIdx.x * 32, c0 = blockIdx.y * 32;
  const int tid = threadIdx.x;
  {
    const int r = tid >> 3, cq = (tid & 7) * 4;
    float4 v = *(const float4*)(in + ((size_t)e * R + r0 + r) * C + c0 + cq);
    t[r][cq + 0] = f2bf(v.x); t[r][cq + 1] = f2bf(v.y);
    t[r][cq + 2] = f2bf(v.z); t[r][cq + 3] = f2bf(v.w);
  }
  __syncthreads();
  {
    const int c = tid >> 3, rq = (tid & 7) * 4;
    u16x4 o;
    o.x = t[rq + 0][c]; o.y = t[rq + 1][c]; o.z = t[rq + 2][c]; o.w = t[rq + 3][c];
    *(u16x4*)(out + ((size_t)e * C + c0 + c) * R + r0 + rq) = o;
  }
}

// ---------------- fused gating ----------------
// 256 threads, 32 tokens/block, BN=256 (full), BK=32.
// Thread (tm=tid>>5, tn=tid&31): 4 tokens (tm*4..+3) x 8 cols ({tn*4+j, 128+tn*4+j}).
// GEMM2 + softmax + top2 fully in registers via butterfly shuffle. Emits xb (bf16 x).
__global__ __launch_bounds__(256, 4) void gating_fused_kernel(
    const float* __restrict__ x, const float* __restrict__ wg1,
    const float* __restrict__ bg1, const float* __restrict__ wg2,
    const float* __restrict__ bg2, float* __restrict__ gates,
    u16* __restrict__ xb) {
  __shared__ float As[32][36];      // transposed x chunk [k][m]
  __shared__ float Bs[32 * 256];    // wg1 chunk [k][n], linear for global_load_lds
  const int tid = threadIdx.x;
  const int lane = tid & 63, w = tid >> 6;
  const int tn = tid & 31, tm = tid >> 5;
  const int t0 = blockIdx.x * 32;

  float acc[4][8];
  #pragma unroll
  for (int i = 0; i < 4; ++i)
    #pragma unroll
    for (int j = 0; j < 8; ++j) acc[i][j] = 0.f;

  const int srow = tid >> 3, sc4 = (tid & 7) * 4;
  for (int k0 = 0; k0 < 1024; k0 += 32) {
    __syncthreads();
    // stage wg1 chunk [32][256] f32 via global_load_lds: wave w -> k rows w*8..w*8+7
    {
      const char* g = (const char*)wg1 + (size_t)(k0 + w * 8) * 1024 + lane * 16;
      char* l = (char*)Bs + w * 8192;
      #pragma unroll
      for (int i = 0; i < 8; ++i) gld16(g + i * 1024, l + i * 1024);
    }
    // stage x chunk transposed + emit bf16 x (each thread one float4)
    {
      const float* src = x + (size_t)(t0 + srow) * 1024 + k0 + sc4;
      float4 v = *(const float4*)src;
      As[sc4 + 0][srow] = v.x; As[sc4 + 1][srow] = v.y;
      As[sc4 + 2][srow] = v.z; As[sc4 + 3][srow] = v.w;
      u16x4 o; o.x = f2bf(v.x); o.y = f2bf(v.y); o.z = f2bf(v.z); o.w = f2bf(v.w);
      *(u16x4*)(xb + (size_t)(t0 + srow) * 1024 + k0 + sc4) = o;
    }
    __syncthreads();
    #pragma unroll 4
    for (int kk = 0; kk < 32; ++kk) {
      float4 a4 = *(const float4*)&As[kk][tm * 4];
      float4 b0 = *(const float4*)&Bs[kk * 256 + tn * 4];
      float4 b1 = *(const float4*)&Bs[kk * 256 + 128 + tn * 4];
      float av[4] = {a4.x, a4.y, a4.z, a4.w};
      float bv[8] = {b0.x, b0.y, b0.z, b0.w, b1.x, b1.y, b1.z, b1.w};
      #pragma unroll
      for (int i = 0; i < 4; ++i)
        #pragma unroll
        for (int j = 0; j < 8; ++j) acc[i][j] += av[i] * bv[j];
    }
  }

  // bias + gelu + GEMM2 partials over this thread's 8 cols
  float bb[8];
  {
    float4 ba = *(const float4*)&bg1[tn * 4];
    float4 bc = *(const float4*)&bg1[128 + tn * 4];
    bb[0] = ba.x; bb[1] = ba.y; bb[2] = ba.z; bb[3] = ba.w;
    bb[4] = bc.x; bb[5] = bc.y; bb[6] = bc.z; bb[7] = bc.w;
  }
  float part[4][8];
  #pragma unroll
  for (int i = 0; i < 4; ++i)
    #pragma unroll
    for (int e = 0; e < 8; ++e) part[i][e] = 0.f;
  #pragma unroll
  for (int j = 0; j < 8; ++j) {
    const int col = (j < 4) ? (tn * 4 + j) : (128 + tn * 4 + (j - 4));
    float4 wa = *(const float4*)&wg2[col * 8];
    float4 wb = *(const float4*)&wg2[col * 8 + 4];
    float we[8] = {wa.x, wa.y, wa.z, wa.w, wb.x, wb.y, wb.z, wb.w};
    #pragma unroll
    for (int i = 0; i < 4; ++i) {
      float h = gelu_exact(acc[i][j] + bb[j]);
      #pragma unroll
      for (int e = 0; e < 8; ++e) part[i][e] += h * we[e];
    }
  }
  // butterfly reduce over the 32-thread tn group (masks 1..16 stay in 32-lane half)
  #pragma unroll
  for (int mask = 1; mask < 32; mask <<= 1)
    #pragma unroll
    for (int i = 0; i < 4; ++i)
      #pragma unroll
      for (int e = 0; e < 8; ++e) part[i][e] += __shfl_xor(part[i][e], mask);

  // softmax + top2: lane tn=i handles token tm*4+i
  if (tn < 4) {
    float lg[8];
    #pragma unroll
    for (int i = 0; i < 4; ++i)
      if (tn == i) {
        #pragma unroll
        for (int e = 0; e < 8; ++e) lg[e] = part[i][e];
      }
    #pragma unroll
    for (int e = 0; e < 8; ++e) lg[e] += bg2[e];
    float m = lg[0];
    #pragma unroll
    for (int e = 1; e < 8; ++e) m = fmaxf(m, lg[e]);
    float ex[8], s = 0.f;
    #pragma unroll
    for (int e = 0; e < 8; ++e) { ex[e] = expf(lg[e] - m); s += ex[e]; }
    int i1 = 0;
    #pragma unroll
    for (int e = 1; e < 8; ++e) if (lg[e] > lg[i1]) i1 = e;   // strict >: lowest idx on tie
    int i2 = (i1 == 0) ? 1 : 0;
    #pragma unroll
    for (int e = 0; e < 8; ++e) if (e != i1 && lg[e] > lg[i2]) i2 = e;
    float inv = 1.f / s;
    float go[8];
    #pragma unroll
    for (int e = 0; e < 8; ++e) go[e] = (e == i1 || e == i2) ? ex[e] * inv : 0.f;
    float* gp = &gates[(size_t)(t0 + tm * 4 + tn) * 8];
    *(float4*)gp = make_float4(go[0], go[1], go[2], go[3]);
    *(float4*)(gp + 4) = make_float4(go[4], go[5], go[6], go[7]);
  }
}

// ---------------- pass A: h_all[e][t][h] = gate[t,e]*gelu(x@W1e + b1e), bf16 ----------------
__global__ __launch_bounds__(256) void expert_h_kernel(
    const u16* __restrict__ xb, const u16* __restrict__ w1t,
    const float* __restrict__ b1, const float* __restrict__ gates,
    u16* __restrict__ h_all) {
  __shared__ u16 As[128 * 64];
  __shared__ u16 Bs[128 * 64];
  __shared__ float gate_s[128];
  __shared__ float b1_s[128];
  const int tid = threadIdx.x, lane = tid & 63, wid = tid >> 6;
  const int e = blockIdx.z;
  const int t0 = blockIdx.x * 128;
  const int n0 = blockIdx.y * 128;
  const int wm = wid >> 1, wn = wid & 1;

  if (tid < 128) {
    gate_s[tid] = gates[(size_t)(t0 + tid) * 8 + e];
    b1_s[tid] = b1[e * 256 + n0 + tid];
  }

  f32x4 acc[4][4];
  #pragma unroll
  for (int i = 0; i < 4; ++i)
    #pragma unroll
    for (int j = 0; j < 4; ++j) acc[i][j] = (f32x4){0.f, 0.f, 0.f, 0.f};

  const char* Ab = (const char*)xb + (size_t)t0 * 2048;
  const char* Bb = (const char*)w1t + ((size_t)e * 256 + n0) * 2048;
  for (int kt = 0; kt < 16; ++kt) {
    __syncthreads();
    stage_tile(As, Ab + kt * 128, 2048, wid, lane);
    stage_tile(Bs, Bb + kt * 128, 2048, wid, lane);
    __syncthreads();
    mma_step(As, Bs, acc, wm, wn, lane);
  }

  #pragma unroll
  for (int mf = 0; mf < 4; ++mf)
    #pragma unroll
    for (int rr = 0; rr < 4; ++rr) {
      const int lt = wm * 64 + mf * 16 + ((lane >> 4) << 2) + rr;
      const float g = gate_s[lt];
      #pragma unroll
      for (int nf = 0; nf < 4; ++nf) {
        const int ln = wn * 64 + nf * 16 + (lane & 15);
        float u = acc[mf][nf][rr] + b1_s[ln];
        float h = gelu_exact(u);
        h_all[((size_t)e * T_TOK + t0 + lt) * 256 + n0 + ln] = f2bf(h * g);
      }
    }
}

// ---------------- pass B: y = sum_e h_all_e @ W2e + sum_e gate*b2 ----------------
__global__ __launch_bounds__(256) void moe_out_kernel(
    const u16* __restrict__ h_all, const u16* __restrict__ w2t,
    const float* __restrict__ b2, const float* __restrict__ gates,
    float* __restrict__ y) {
  __shared__ u16 As[128 * 64];
  __shared__ u16 Bs[128 * 64];
  __shared__ float gate_s[128][8];
  __shared__ float b2_s[8][128];
  const int tid = threadIdx.x, lane = tid & 63, wid = tid >> 6;
  const int t0 = blockIdx.x * 128;
  const int n0 = blockIdx.y * 128;
  const int wm = wid >> 1, wn = wid & 1;

  for (int i = tid; i < 1024; i += 256) {
    gate_s[i >> 3][i & 7] = gates[(size_t)(t0 + (i >> 3)) * 8 + (i & 7)];
    b2_s[i >> 7][i & 127] = b2[(size_t)(i >> 7) * 1024 + n0 + (i & 127)];
  }

  f32x4 acc[4][4];
  #pragma unroll
  for (int i = 0; i < 4; ++i)
    #pragma unroll
    for (int j = 0; j < 4; ++j) acc[i][j] = (f32x4){0.f, 0.f, 0.f, 0.f};

  for (int e = 0; e < NE; ++e) {
    const char* Ab = (const char*)h_all + ((size_t)e * T_TOK + t0) * 512;
    const char* Bb = (const char*)w2t + ((size_t)e * D_DIM + n0) * 512;
    #pragma unroll 1
    for (int kt = 0; kt < 4; ++kt) {
      __syncthreads();
      stage_tile(As, Ab + kt * 128, 512, wid, lane);
      stage_tile(Bs, Bb + kt * 128, 512, wid, lane);
      __syncthreads();
      mma_step(As, Bs, acc, wm, wn, lane);
    }
  }

  #pragma unroll
  for (int mf = 0; mf < 4; ++mf)
    #pragma unroll
    for (int rr = 0; rr < 4; ++rr) {
      const int lt = wm * 64 + mf * 16 + ((lane >> 4) << 2) + rr;
      float g8[8];
      #pragma unroll
      for (int e = 0; e < 8; ++e) g8[e] = gate_s[lt][e];
      #pragma unroll
      for (int nf = 0; nf < 4; ++nf) {
        const int ln = wn * 64 + nf * 16 + (lane & 15);
        float bias = 0.f;
        #pragma unroll
        for (int e = 0; e < 8; ++e) bias += g8[e] * b2_s[e][ln];
        y[(size_t)(t0 + lt) * 1024 + n0 + ln] = acc[mf][nf][rr] + bias;
      }
    }
}

extern "C" void kernel_launch(void* const* d_in, const int* in_sizes, int n_in,
                              void* d_out, int out_size, void* d_ws, size_t ws_size,
                              hipStream_t stream) {
  (void)in_sizes; (void)n_in; (void)out_size; (void)ws_size;
  const float* x   = (const float*)d_in[0];
  const float* wg1 = (const float*)d_in[1];
  const float* bg1 = (const float*)d_in[2];
  const float* wg2 = (const float*)d_in[3];
  const float* bg2 = (const float*)d_in[4];
  const float* w1  = (const float*)d_in[5];
  const float* b1  = (const float*)d_in[6];
  const float* w2  = (const float*)d_in[7];
  const float* b2  = (const float*)d_in[8];
  float* y = (float*)d_out;

  char* ws = (char*)d_ws;
  u16*   xb    = (u16*)(ws);                       // 33,554,432 B
  u16*   w1t   = (u16*)(ws + 33554432);            //  4,194,304 B
  u16*   w2t   = (u16*)(ws + 37748736);            //  4,194,304 B
  float* gates = (float*)(ws + 41943040);          //    524,288 B
  u16*   h_all = (u16*)(ws + 42467328);            // 67,108,864 B  (total ~104.5 MiB)

  // w1[e][1024][256] -> w1t[e][256][1024]; w2[e][256][1024] -> w2t[e][1024][256]
  transpose_cvt_kernel<<<dim3(32, 8, 8), 256, 0, stream>>>(w1, w1t, 1024, 256);
  transpose_cvt_kernel<<<dim3(8, 32, 8), 256, 0, stream>>>(w2, w2t, 256, 1024);
  gating_fused_kernel<<<512, 256, 0, stream>>>(x, wg1, bg1, wg2, bg2, gates, xb);
  expert_h_kernel<<<dim3(128, 2, 8), 256, 0, stream>>>(xb, w1t, b1, gates, h_all);
  moe_out_kernel <<<dim3(128, 8), 256, 0, stream>>>(h_all, w2t, b2, gates, y);
}

// Round 4
// 358.037 us; speedup vs baseline: 1.1836x; 1.0486x over previous
//
#include <hip/hip_runtime.h>

typedef unsigned short u16;
typedef __attribute__((ext_vector_type(8))) short bf16x8;
typedef __attribute__((ext_vector_type(4))) float f32x4;
typedef __attribute__((ext_vector_type(4))) u16 u16x4;

#define T_TOK 16384
#define D_DIM 1024
#define NE 8

__device__ __forceinline__ u16 f2bf(float f) {
  union { float f; unsigned int u; } c; c.f = f;
  unsigned int u = c.u;
  u += 0x7fffu + ((u >> 16) & 1u);   // round-to-nearest-even
  return (u16)(u >> 16);
}

__device__ __forceinline__ float gelu_exact(float u) {
  return 0.5f * u * (1.0f + erff(u * 0.70710678118654752f));
}

__device__ __forceinline__ void gld16(const void* g, void* l) {
  __builtin_amdgcn_global_load_lds(
      (const __attribute__((address_space(1))) unsigned int*)g,
      (__attribute__((address_space(3))) unsigned int*)l, 16, 0, 0);
}

// Stage a 128-row x 64-col bf16 tile (128 bytes per row) into linear LDS [128][64].
__device__ __forceinline__ void stage_tile(u16* lds, const char* g0, size_t stride,
                                           int wid, int lane) {
  const char* g = g0 + (size_t)(wid * 8 + (lane >> 3)) * stride + (size_t)((lane & 7) * 16);
  char* l = (char*)lds + wid * 1024;   // wave-uniform LDS base; HW adds lane*16
  #pragma unroll
  for (int c = 0; c < 4; ++c)
    gld16(g + (size_t)(32 * c) * stride, l + c * 4096);
}

// One BK=64 step: 32 MFMA per wave, acc[4][4] (64x64 per wave, 2x2 waves = 128x128)
__device__ __forceinline__ void mma_step(const u16* As, const u16* Bs, f32x4 acc[4][4],
                                         int wm, int wn, int lane) {
  const int r = lane & 15, kq = (lane >> 4) * 8;
  #pragma unroll
  for (int ks = 0; ks < 2; ++ks) {
    const int col = ks * 32 + kq;
    bf16x8 a[4], b[4];
    #pragma unroll
    for (int mf = 0; mf < 4; ++mf)
      a[mf] = *(const bf16x8*)&As[(wm * 64 + mf * 16 + r) * 64 + col];
    #pragma unroll
    for (int nf = 0; nf < 4; ++nf)
      b[nf] = *(const bf16x8*)&Bs[(wn * 64 + nf * 16 + r) * 64 + col];
    #pragma unroll
    for (int mf = 0; mf < 4; ++mf)
      #pragma unroll
      for (int nf = 0; nf < 4; ++nf)
        acc[mf][nf] = __builtin_amdgcn_mfma_f32_16x16x32_bf16(a[mf], b[nf], acc[mf][nf], 0, 0, 0);
  }
}

// ---------------- tiled transpose+convert: in[e][R][C] f32 -> out[e][C][R] bf16 ----------------
__global__ __launch_bounds__(256) void transpose_cvt_kernel(const float* __restrict__ in,
                                                            u16* __restrict__ out,
                                                            int R, int C) {
  __shared__ u16 t[32][36];
  const int e = blockIdx.z;
  const int r0 = blockIdx.x * 32, c0 = blockIdx.y * 32;
  const int tid = threadIdx.x;
  {
    const int r = tid >> 3, cq = (tid & 7) * 4;
    float4 v = *(const float4*)(in + ((size_t)e * R + r0 + r) * C + c0 + cq);
    t[r][cq + 0] = f2bf(v.x); t[r][cq + 1] = f2bf(v.y);
    t[r][cq + 2] = f2bf(v.z); t[r][cq + 3] = f2bf(v.w);
  }
  __syncthreads();
  {
    const int c = tid >> 3, rq = (tid & 7) * 4;
    u16x4 o;
    o.x = t[rq + 0][c]; o.y = t[rq + 1][c]; o.z = t[rq + 2][c]; o.w = t[rq + 3][c];
    *(u16x4*)(out + ((size_t)e * C + c0 + c) * R + r0 + rq) = o;
  }
}

// ---------------- fused gating (double-buffered 2-phase pipeline) ----------------
// 256 threads, 32 tokens/block, BN=256 (full), BK=32.
// Thread (tm=tid>>5, tn=tid&31): 4 tokens (tm*4..+3) x 8 cols ({tn*4+j, 128+tn*4+j}).
// Per iter: issue next-tile gld16 + x prefetch BEFORE compute; write x-transpose after
// compute; ONE barrier per iter. GEMM2/softmax/top2 in registers via butterfly shuffle.
__global__ __launch_bounds__(256, 2) void gating_fused_kernel(
    const float* __restrict__ x, const float* __restrict__ wg1,
    const float* __restrict__ bg1, const float* __restrict__ wg2,
    const float* __restrict__ bg2, float* __restrict__ gates,
    u16* __restrict__ xb) {
  __shared__ float As[2][32][36];    // transposed x chunk [k][m]
  __shared__ float Bs[2][32 * 256];  // wg1 chunk [k][n], linear for global_load_lds
  const int tid = threadIdx.x;
  const int lane = tid & 63, w = tid >> 6;
  const int tn = tid & 31, tm = tid >> 5;
  const int t0 = blockIdx.x * 32;
  const int srow = tid >> 3, sc4 = (tid & 7) * 4;

  float acc[4][8];
  #pragma unroll
  for (int i = 0; i < 4; ++i)
    #pragma unroll
    for (int j = 0; j < 8; ++j) acc[i][j] = 0.f;

  // ---- prologue: stage k0=0 into buffer 0 ----
  {
    const char* g = (const char*)wg1 + (size_t)(w * 8) * 1024 + lane * 16;
    char* l = (char*)&Bs[0][0] + w * 8192;
    #pragma unroll
    for (int i = 0; i < 8; ++i) gld16(g + i * 1024, l + i * 1024);
  }
  {
    const float* src = x + (size_t)(t0 + srow) * 1024 + sc4;
    float4 v = *(const float4*)src;
    As[0][sc4 + 0][srow] = v.x; As[0][sc4 + 1][srow] = v.y;
    As[0][sc4 + 2][srow] = v.z; As[0][sc4 + 3][srow] = v.w;
    u16x4 o; o.x = f2bf(v.x); o.y = f2bf(v.y); o.z = f2bf(v.z); o.w = f2bf(v.w);
    *(u16x4*)(xb + (size_t)(t0 + srow) * 1024 + sc4) = o;
  }
  __syncthreads();

  int cur = 0;
  for (int k0 = 0; k0 < 1024; k0 += 32) {
    const bool has_next = (k0 + 32) < 1024;
    float4 xv;
    if (has_next) {
      // issue next wg1 tile into buf cur^1 (stays in flight across compute)
      const char* g = (const char*)wg1 + (size_t)(k0 + 32 + w * 8) * 1024 + lane * 16;
      char* l = (char*)&Bs[cur ^ 1][0] + w * 8192;
      #pragma unroll
      for (int i = 0; i < 8; ++i) gld16(g + i * 1024, l + i * 1024);
      // issue next x chunk load into registers
      xv = *(const float4*)(x + (size_t)(t0 + srow) * 1024 + k0 + 32 + sc4);
    }
    // compute current tile
    #pragma unroll 4
    for (int kk = 0; kk < 32; ++kk) {
      float4 a4 = *(const float4*)&As[cur][kk][tm * 4];
      float4 b0 = *(const float4*)&Bs[cur][kk * 256 + tn * 4];
      float4 b1 = *(const float4*)&Bs[cur][kk * 256 + 128 + tn * 4];
      float av[4] = {a4.x, a4.y, a4.z, a4.w};
      float bv[8] = {b0.x, b0.y, b0.z, b0.w, b1.x, b1.y, b1.z, b1.w};
      #pragma unroll
      for (int i = 0; i < 4; ++i)
        #pragma unroll
        for (int j = 0; j < 8; ++j) acc[i][j] += av[i] * bv[j];
    }
    if (has_next) {
      // write-late: x transpose into next buffer + bf16 emit (xv load hid under compute)
      As[cur ^ 1][sc4 + 0][srow] = xv.x; As[cur ^ 1][sc4 + 1][srow] = xv.y;
      As[cur ^ 1][sc4 + 2][srow] = xv.z; As[cur ^ 1][sc4 + 3][srow] = xv.w;
      u16x4 o; o.x = f2bf(xv.x); o.y = f2bf(xv.y); o.z = f2bf(xv.z); o.w = f2bf(xv.w);
      *(u16x4*)(xb + (size_t)(t0 + srow) * 1024 + k0 + 32 + sc4) = o;
    }
    __syncthreads();
    cur ^= 1;
  }

  // bias + gelu + GEMM2 partials over this thread's 8 cols
  float bb[8];
  {
    float4 ba = *(const float4*)&bg1[tn * 4];
    float4 bc = *(const float4*)&bg1[128 + tn * 4];
    bb[0] = ba.x; bb[1] = ba.y; bb[2] = ba.z; bb[3] = ba.w;
    bb[4] = bc.x; bb[5] = bc.y; bb[6] = bc.z; bb[7] = bc.w;
  }
  float part[4][8];
  #pragma unroll
  for (int i = 0; i < 4; ++i)
    #pragma unroll
    for (int e = 0; e < 8; ++e) part[i][e] = 0.f;
  #pragma unroll
  for (int j = 0; j < 8; ++j) {
    const int col = (j < 4) ? (tn * 4 + j) : (128 + tn * 4 + (j - 4));
    float4 wa = *(const float4*)&wg2[col * 8];
    float4 wb = *(const float4*)&wg2[col * 8 + 4];
    float we[8] = {wa.x, wa.y, wa.z, wa.w, wb.x, wb.y, wb.z, wb.w};
    #pragma unroll
    for (int i = 0; i < 4; ++i) {
      float h = gelu_exact(acc[i][j] + bb[j]);
      #pragma unroll
      for (int e = 0; e < 8; ++e) part[i][e] += h * we[e];
    }
  }
  // butterfly reduce over the 32-thread tn group (masks 1..16 stay in 32-lane half)
  #pragma unroll
  for (int mask = 1; mask < 32; mask <<= 1)
    #pragma unroll
    for (int i = 0; i < 4; ++i)
      #pragma unroll
      for (int e = 0; e < 8; ++e) part[i][e] += __shfl_xor(part[i][e], mask);

  // softmax + top2: lane tn=i handles token tm*4+i
  if (tn < 4) {
    float lg[8];
    #pragma unroll
    for (int i = 0; i < 4; ++i)
      if (tn == i) {
        #pragma unroll
        for (int e = 0; e < 8; ++e) lg[e] = part[i][e];
      }
    #pragma unroll
    for (int e = 0; e < 8; ++e) lg[e] += bg2[e];
    float m = lg[0];
    #pragma unroll
    for (int e = 1; e < 8; ++e) m = fmaxf(m, lg[e]);
    float ex[8], s = 0.f;
    #pragma unroll
    for (int e = 0; e < 8; ++e) { ex[e] = expf(lg[e] - m); s += ex[e]; }
    int i1 = 0;
    #pragma unroll
    for (int e = 1; e < 8; ++e) if (lg[e] > lg[i1]) i1 = e;   // strict >: lowest idx on tie
    int i2 = (i1 == 0) ? 1 : 0;
    #pragma unroll
    for (int e = 0; e < 8; ++e) if (e != i1 && lg[e] > lg[i2]) i2 = e;
    float inv = 1.f / s;
    float go[8];
    #pragma unroll
    for (int e = 0; e < 8; ++e) go[e] = (e == i1 || e == i2) ? ex[e] * inv : 0.f;
    float* gp = &gates[(size_t)(t0 + tm * 4 + tn) * 8];
    *(float4*)gp = make_float4(go[0], go[1], go[2], go[3]);
    *(float4*)(gp + 4) = make_float4(go[4], go[5], go[6], go[7]);
  }
}

// ---------------- pass A: h_all[e][t][h] = gate[t,e]*gelu(x@W1e + b1e), bf16 ----------------
__global__ __launch_bounds__(256) void expert_h_kernel(
    const u16* __restrict__ xb, const u16* __restrict__ w1t,
    const float* __restrict__ b1, const float* __restrict__ gates,
    u16* __restrict__ h_all) {
  __shared__ u16 As[128 * 64];
  __shared__ u16 Bs[128 * 64];
  __shared__ float gate_s[128];
  __shared__ float b1_s[128];
  const int tid = threadIdx.x, lane = tid & 63, wid = tid >> 6;
  const int e = blockIdx.z;
  const int t0 = blockIdx.x * 128;
  const int n0 = blockIdx.y * 128;
  const int wm = wid >> 1, wn = wid & 1;

  if (tid < 128) {
    gate_s[tid] = gates[(size_t)(t0 + tid) * 8 + e];
    b1_s[tid] = b1[e * 256 + n0 + tid];
  }

  f32x4 acc[4][4];
  #pragma unroll
  for (int i = 0; i < 4; ++i)
    #pragma unroll
    for (int j = 0; j < 4; ++j) acc[i][j] = (f32x4){0.f, 0.f, 0.f, 0.f};

  const char* Ab = (const char*)xb + (size_t)t0 * 2048;
  const char* Bb = (const char*)w1t + ((size_t)e * 256 + n0) * 2048;
  for (int kt = 0; kt < 16; ++kt) {
    __syncthreads();
    stage_tile(As, Ab + kt * 128, 2048, wid, lane);
    stage_tile(Bs, Bb + kt * 128, 2048, wid, lane);
    __syncthreads();
    mma_step(As, Bs, acc, wm, wn, lane);
  }

  #pragma unroll
  for (int mf = 0; mf < 4; ++mf)
    #pragma unroll
    for (int rr = 0; rr < 4; ++rr) {
      const int lt = wm * 64 + mf * 16 + ((lane >> 4) << 2) + rr;
      const float g = gate_s[lt];
      #pragma unroll
      for (int nf = 0; nf < 4; ++nf) {
        const int ln = wn * 64 + nf * 16 + (lane & 15);
        float u = acc[mf][nf][rr] + b1_s[ln];
        float h = gelu_exact(u);
        h_all[((size_t)e * T_TOK + t0 + lt) * 256 + n0 + ln] = f2bf(h * g);
      }
    }
}

// ---------------- pass B: y = sum_e h_all_e @ W2e + sum_e gate*b2 ----------------
__global__ __launch_bounds__(256) void moe_out_kernel(
    const u16* __restrict__ h_all, const u16* __restrict__ w2t,
    const float* __restrict__ b2, const float* __restrict__ gates,
    float* __restrict__ y) {
  __shared__ u16 As[128 * 64];
  __shared__ u16 Bs[128 * 64];
  __shared__ float gate_s[128][8];
  __shared__ float b2_s[8][128];
  const int tid = threadIdx.x, lane = tid & 63, wid = tid >> 6;
  const int t0 = blockIdx.x * 128;
  const int n0 = blockIdx.y * 128;
  const int wm = wid >> 1, wn = wid & 1;

  for (int i = tid; i < 1024; i += 256) {
    gate_s[i >> 3][i & 7] = gates[(size_t)(t0 + (i >> 3)) * 8 + (i & 7)];
    b2_s[i >> 7][i & 127] = b2[(size_t)(i >> 7) * 1024 + n0 + (i & 127)];
  }

  f32x4 acc[4][4];
  #pragma unroll
  for (int i = 0; i < 4; ++i)
    #pragma unroll
    for (int j = 0; j < 4; ++j) acc[i][j] = (f32x4){0.f, 0.f, 0.f, 0.f};

  for (int e = 0; e < NE; ++e) {
    const char* Ab = (const char*)h_all + ((size_t)e * T_TOK + t0) * 512;
    const char* Bb = (const char*)w2t + ((size_t)e * D_DIM + n0) * 512;
    #pragma unroll 1
    for (int kt = 0; kt < 4; ++kt) {
      __syncthreads();
      stage_tile(As, Ab + kt * 128, 512, wid, lane);
      stage_tile(Bs, Bb + kt * 128, 512, wid, lane);
      __syncthreads();
      mma_step(As, Bs, acc, wm, wn, lane);
    }
  }

  #pragma unroll
  for (int mf = 0; mf < 4; ++mf)
    #pragma unroll
    for (int rr = 0; rr < 4; ++rr) {
      const int lt = wm * 64 + mf * 16 + ((lane >> 4) << 2) + rr;
      float g8[8];
      #pragma unroll
      for (int e = 0; e < 8; ++e) g8[e] = gate_s[lt][e];
      #pragma unroll
      for (int nf = 0; nf < 4; ++nf) {
        const int ln = wn * 64 + nf * 16 + (lane & 15);
        float bias = 0.f;
        #pragma unroll
        for (int e = 0; e < 8; ++e) bias += g8[e] * b2_s[e][ln];
        y[(size_t)(t0 + lt) * 1024 + n0 + ln] = acc[mf][nf][rr] + bias;
      }
    }
}

extern "C" void kernel_launch(void* const* d_in, const int* in_sizes, int n_in,
                              void* d_out, int out_size, void* d_ws, size_t ws_size,
                              hipStream_t stream) {
  (void)in_sizes; (void)n_in; (void)out_size; (void)ws_size;
  const float* x   = (const float*)d_in[0];
  const float* wg1 = (const float*)d_in[1];
  const float* bg1 = (const float*)d_in[2];
  const float* wg2 = (const float*)d_in[3];
  const float* bg2 = (const float*)d_in[4];
  const float* w1  = (const float*)d_in[5];
  const float* b1  = (const float*)d_in[6];
  const float* w2  = (const float*)d_in[7];
  const float* b2  = (const float*)d_in[8];
  float* y = (float*)d_out;

  char* ws = (char*)d_ws;
  u16*   xb    = (u16*)(ws);                       // 33,554,432 B
  u16*   w1t   = (u16*)(ws + 33554432);            //  4,194,304 B
  u16*   w2t   = (u16*)(ws + 37748736);            //  4,194,304 B
  float* gates = (float*)(ws + 41943040);          //    524,288 B
  u16*   h_all = (u16*)(ws + 42467328);            // 67,108,864 B  (total ~104.5 MiB)

  // w1[e][1024][256] -> w1t[e][256][1024]; w2[e][256][1024] -> w2t[e][1024][256]
  transpose_cvt_kernel<<<dim3(32, 8, 8), 256, 0, stream>>>(w1, w1t, 1024, 256);
  transpose_cvt_kernel<<<dim3(8, 32, 8), 256, 0, stream>>>(w2, w2t, 256, 1024);
  gating_fused_kernel<<<512, 256, 0, stream>>>(x, wg1, bg1, wg2, bg2, gates, xb);
  expert_h_kernel<<<dim3(128, 2, 8), 256, 0, stream>>>(xb, w1t, b1, gates, h_all);
  moe_out_kernel <<<dim3(128, 8), 256, 0, stream>>>(h_all, w2t, b2, gates, y);
}